// Round 5
// baseline (982.844 us; speedup 1.0000x reference)
//
#include <hip/hip_runtime.h>
#include <hip/hip_fp16.h>
#include <cstdint>

#define DEV static __device__ __forceinline__

typedef _Float16 h2v __attribute__((ext_vector_type(2)));
typedef _Float16 half8 __attribute__((ext_vector_type(8)));
typedef float float4v __attribute__((ext_vector_type(4)));

union U32H2 { uint32_t u; _Float16 f[2]; };

DEV uint32_t pack_f2(float a, float b) {
    auto p = __builtin_amdgcn_cvt_pkrtz(a, b);
    return __builtin_bit_cast(uint32_t, p);
}

DEV float dot2acc(uint32_t w, uint32_t h, float acc) {
    return __builtin_amdgcn_fdot2(__builtin_bit_cast(h2v, w),
                                  __builtin_bit_cast(h2v, h), acc, false);
}

DEV half8 bc8(uint4 v) { return __builtin_bit_cast(half8, v); }

DEV float sigmoidf_(float x) { return 1.0f / (1.0f + __expf(-x)); }
DEV float tanh_fast(float x) { float e = __expf(-2.0f*x); return (1.0f - e) / (1.0f + e); }

DEV void gl_lds16(const void* gsrc, void* ldst) {
    __builtin_amdgcn_global_load_lds(
        (const __attribute__((address_space(1))) uint32_t*)gsrc,
        (__attribute__((address_space(3))) uint32_t*)ldst, 16, 0, 0);
}

// ---------------- workspace layout (uint32 units) ----------------
// N=384 H=256 Z=128 ED=128 AH=64
static const size_t OFF_W16T  = 0;          // 98304  : Whh f16, k_gru K-split per-thread-chunk layout
static const size_t OFF_GI    = 98304;      // 768
static const size_t OFF_CC    = 99072;      // 128
static const size_t OFF_BF    = 99200;      // 65536  : W2A in MFMA B-frag layout
static const size_t OFF_NODES = 164736;     // 98304  : GRU outputs fp32 [384][256]
static const size_t OFF_PF    = 263040;     // 196608 : P in MFMA A-frag layout
static const size_t OFF_QF    = 459648;     // 196608 : Q natural f16 [384][512 u32]
static const size_t OFF_R0    = 656256;     // 24576
static const size_t OFF_R1    = 680832;     // 24576
static const size_t OFF_TT    = 705408;     // 9437184: T f16 [s][d][64 u32]
static const size_t OFF_ATT0  = 10142592;   // 147456
static const size_t OFF_ATT1  = 10290048;   // 147456
static const size_t OFF_AGG   = 10437504;   // 98304
static const size_t OFF_X0    = 10535808;   // 98304
static const size_t OFF_CS    = 10634112;   // 384
static const size_t OFF_V     = 10634496;   // 256
static const size_t WS_TOTAL  = 10634752;   // u32 elems (~42.5 MB)

// ---------------- prep kernels ----------------
// WL layout for K-split GRU: uint4 index o4 = c*512 + t  (c=0..47, t=0..511)
// thread t: unit r = t>>1, K-half = t&1. chunk c: gate j = c>>4, k-slice c16 = c&15.
__global__ void k_prep_w16(const float* __restrict__ Whh, uint32_t* __restrict__ WL) {
    int o4 = blockIdx.x * 256 + threadIdx.x;           // < 24576
    int c = o4 >> 9, t = o4 & 511;
    int j = c >> 4, c16 = c & 15;
    int row = (t >> 1) + 256*j;
    int k0 = (t & 1)*128 + c16*8;
    const float* src = Whh + row*256 + k0;
    uint4 o;
    o.x = pack_f2(src[0], src[1]);
    o.y = pack_f2(src[2], src[3]);
    o.z = pack_f2(src[4], src[5]);
    o.w = pack_f2(src[6], src[7]);
    ((uint4*)WL)[o4] = o;
}

__global__ void k_prep_gi(const float* __restrict__ z, const float* __restrict__ Wih,
                          const float* __restrict__ bih, float* __restrict__ gi) {
    int o = blockIdx.x * 256 + threadIdx.x;            // < 768
    float acc = bih[o];
    for (int i = 0; i < 128; ++i) acc += Wih[o*128 + i] * z[i];
    gi[o] = acc;
}

__global__ void k_prep_cc(const float* __restrict__ eg_b2, const float* __restrict__ a0W1,
                          const float* __restrict__ a1W1, float* __restrict__ cc) {
    int t = threadIdx.x;                               // < 128
    const float* A = (t < 64) ? a0W1 : a1W1;
    int j = t & 63;
    float acc = 0.f;
    for (int i = 0; i < 128; ++i) acc += eg_b2[i] * A[i*64 + j];
    cc[t] = acc;
}

// W2A[k][n] in MFMA B-frag layout
__global__ void k_prep_w2a(const float* __restrict__ eg_W2, const float* __restrict__ a0W1,
                           const float* __restrict__ a1W1, uint32_t* __restrict__ BF) {
    int idx = blockIdx.x * 256 + threadIdx.x;          // < 65536
    int k2 = idx >> 7, n = idx & 127;
    const float* A = (n < 64) ? (a0W1 + n) : (a1W1 + (n - 64));
    const float* w0 = eg_W2 + (2*k2) * 128;
    float a = 0.f, b = 0.f;
    for (int i = 0; i < 128; ++i) {
        float av = A[i*64];
        a += w0[i] * av;
        b += w0[128 + i] * av;
    }
    int kk = k2 >> 4, jgrp = (k2 >> 2) & 3, sub = k2 & 3;
    int lane = jgrp*16 + (n & 15), t = n >> 4;
    BF[((kk*8 + t)*64 + lane)*4 + sub] = pack_f2(a, b);
}

// ---------------- GRU: 512 threads, K-split; r/z weights in VGPRs, n-gate in AGPRs ----------------
__global__ void __launch_bounds__(512, 2)
k_gru(const float* __restrict__ gi, const float* __restrict__ bhh,
      const uint32_t* __restrict__ WL, float* __restrict__ nodes) {
    int tid = threadIdx.x;
    int r = tid >> 1, half = tid & 1;
    __shared__ __align__(16) _Float16 hh16[256];

    const uint4* wl4 = (const uint4*)WL;
    // gates r,z: 32 uint4 in arch VGPRs
    uint4 w[32];
    #pragma unroll
    for (int c = 0; c < 32; ++c) w[c] = wl4[c*512 + tid];
    #pragma unroll
    for (int c = 0; c < 32; ++c)
        asm volatile("" : "+v"(w[c].x), "+v"(w[c].y), "+v"(w[c].z), "+v"(w[c].w));
    // gate n: 16 uint4 = 64 u32 parked in AGPRs
    uint32_t wa[64];
    #pragma unroll
    for (int c = 0; c < 16; ++c) {
        uint4 s = wl4[(32 + c)*512 + tid];
        asm volatile("v_accvgpr_write_b32 %0, %1" : "=a"(wa[4*c+0]) : "v"(s.x));
        asm volatile("v_accvgpr_write_b32 %0, %1" : "=a"(wa[4*c+1]) : "v"(s.y));
        asm volatile("v_accvgpr_write_b32 %0, %1" : "=a"(wa[4*c+2]) : "v"(s.z));
        asm volatile("v_accvgpr_write_b32 %0, %1" : "=a"(wa[4*c+3]) : "v"(s.w));
    }

    float bh0 = bhh[r], bh1 = bhh[256 + r], bh2 = bhh[512 + r];
    float gir = gi[r], giz = gi[256 + r], gin = gi[512 + r];
    float h = 0.f;
    if (tid < 128) ((uint32_t*)hh16)[tid] = 0u;
    __syncthreads();

    const uint4* hh4 = (const uint4*)hh16;
    int hbase = half * 16;
    for (int t = 0; t < 384; ++t) {
        float a0 = 0.f, a1 = 0.f, a2 = 0.f;
        #pragma unroll
        for (int c = 0; c < 16; ++c) {
            uint4 hv = hh4[hbase + c];                 // 2-addr wave broadcast (free)
            uint4 w0 = w[c], w1 = w[16 + c];
            uint4 w2;
            asm volatile("v_accvgpr_read_b32 %0, %1" : "=v"(w2.x) : "a"(wa[4*c+0]));
            asm volatile("v_accvgpr_read_b32 %0, %1" : "=v"(w2.y) : "a"(wa[4*c+1]));
            asm volatile("v_accvgpr_read_b32 %0, %1" : "=v"(w2.z) : "a"(wa[4*c+2]));
            asm volatile("v_accvgpr_read_b32 %0, %1" : "=v"(w2.w) : "a"(wa[4*c+3]));
            a0 = dot2acc(w0.x, hv.x, a0); a0 = dot2acc(w0.y, hv.y, a0);
            a0 = dot2acc(w0.z, hv.z, a0); a0 = dot2acc(w0.w, hv.w, a0);
            a1 = dot2acc(w1.x, hv.x, a1); a1 = dot2acc(w1.y, hv.y, a1);
            a1 = dot2acc(w1.z, hv.z, a1); a1 = dot2acc(w1.w, hv.w, a1);
            a2 = dot2acc(w2.x, hv.x, a2); a2 = dot2acc(w2.y, hv.y, a2);
            a2 = dot2acc(w2.z, hv.z, a2); a2 = dot2acc(w2.w, hv.w, a2);
        }
        // merge K-halves (lane pair), add bias
        a0 += __shfl_xor(a0, 1, 64);
        a1 += __shfl_xor(a1, 1, 64);
        a2 += __shfl_xor(a2, 1, 64);
        a0 += bh0; a1 += bh1; a2 += bh2;
        float rg = sigmoidf_(gir + a0);
        float u  = sigmoidf_(giz + a1);
        float n  = tanh_fast(gin + rg * a2);
        h = (1.f - u) * n + u * h;
        __syncthreads();
        if (half == 0) {
            hh16[r] = (_Float16)h;
            nodes[t*256 + r] = h;
        }
        __syncthreads();
    }
}

// ---------------- P (A-frag layout), Q (natural f16), R0 ----------------
__global__ void k_pq(const float* __restrict__ nodes, const float* __restrict__ eg_W1,
                     const float* __restrict__ eg_b1, const float* __restrict__ a0W1,
                     const float* __restrict__ a0b1, const float* __restrict__ cc,
                     uint32_t* __restrict__ PF, uint32_t* __restrict__ QF,
                     float* __restrict__ R0) {
    int tid = threadIdx.x;
    int s0 = blockIdx.x * 4;
    __shared__ float ns[4][256];
    #pragma unroll
    for (int q = 0; q < 4; ++q) ns[q][tid] = nodes[(s0+q)*256 + tid];
    __syncthreads();

    int k0 = tid * 4;
    float acc[4][4];
    #pragma unroll
    for (int q = 0; q < 4; ++q) { acc[q][0]=0;acc[q][1]=0;acc[q][2]=0;acc[q][3]=0; }
    for (int i = 0; i < 256; ++i) {
        float4 wv = *(const float4*)&eg_W1[i*1024 + k0];
        #pragma unroll
        for (int q = 0; q < 4; ++q) {
            float nv = ns[q][i];
            acc[q][0] += nv*wv.x; acc[q][1] += nv*wv.y;
            acc[q][2] += nv*wv.z; acc[q][3] += nv*wv.w;
        }
    }
    float4 bv = *(const float4*)&eg_b1[k0];
    {
        int kk = k0 >> 5;
        int lgrp = ((k0 >> 3) & 3) * 16;
        int sub = (k0 & 7) >> 1;                       // 0 or 2
        #pragma unroll
        for (int q = 0; q < 4; ++q) {
            int s = s0 + q, g = s >> 4, srow = s & 15;
            uint2 pw;
            pw.x = pack_f2(acc[q][0] + bv.x, acc[q][1] + bv.y);
            pw.y = pack_f2(acc[q][2] + bv.z, acc[q][3] + bv.w);
            *(uint2*)(PF + (((g*32 + kk)*64 + lgrp + srow) << 2) + sub) = pw;
        }
    }

    #pragma unroll
    for (int q = 0; q < 4; ++q) { acc[q][0]=0;acc[q][1]=0;acc[q][2]=0;acc[q][3]=0; }
    for (int i = 0; i < 256; ++i) {
        float4 wv = *(const float4*)&eg_W1[(256+i)*1024 + k0];
        #pragma unroll
        for (int q = 0; q < 4; ++q) {
            float nv = ns[q][i];
            acc[q][0] += nv*wv.x; acc[q][1] += nv*wv.y;
            acc[q][2] += nv*wv.z; acc[q][3] += nv*wv.w;
        }
    }
    #pragma unroll
    for (int q = 0; q < 4; ++q) {
        uint2 pw;
        pw.x = pack_f2(acc[q][0], acc[q][1]);
        pw.y = pack_f2(acc[q][2], acc[q][3]);
        ((uint2*)QF)[(s0+q)*256 + tid] = pw;           // QF[d][k/2], natural order
    }

    int srow = tid >> 6, j = tid & 63;
    float racc = a0b1[j] + cc[j];
    for (int i = 0; i < 256; ++i) racc += ns[srow][i] * a0W1[(128+i)*64 + j];
    R0[(s0+srow)*64 + j] = racc;
}

// ---------------- phase A (MFMA): T[s,d,:] = relu(P[s]+Q[d]) @ W2A ----------------
__global__ void __launch_bounds__(256, 2)
k_phaseA_mfma(const uint32_t* __restrict__ PF, const uint32_t* __restrict__ QF,
              const uint32_t* __restrict__ BF, uint32_t* __restrict__ TT) {
    __shared__ __align__(16) char smem[69632];
    uint4* Qs4 = (uint4*)smem;                         // 16 d x 128 uint4 = 32 KB
    uint4* Ps4 = (uint4*)(smem + 32768);               // 4 kk x 64 lane = 4 KB
    uint4* Bs4 = (uint4*)(smem + 36864);               // 4 kk x 8 t x 64 lane = 32 KB

    int tid = threadIdx.x;
    int lane = tid & 63, wv = tid >> 6;
    int g = blockIdx.x, d0 = blockIdx.y * 16;

    {
        const char* src = (const char*)(QF + (size_t)d0 * 512);
        for (int off = wv*1024 + lane*16; off < 32768; off += 4096)
            gl_lds16(src + off, (char*)Qs4 + off);
    }

    float4v acc[4][8];
    #pragma unroll
    for (int t = 0; t < 4; ++t)
        #pragma unroll
        for (int n = 0; n < 8; ++n) acc[t][n] = 0.f;

    for (int c = 0; c < 8; ++c) {
        __syncthreads();
        {
            const char* psrc = (const char*)(PF + (size_t)(g*32 + c*4) * 256);
            for (int off = wv*1024 + lane*16; off < 4096; off += 4096)
                gl_lds16(psrc + off, (char*)Ps4 + off);
            const char* bsrc = (const char*)(BF + (size_t)c * 8192);
            for (int off = wv*1024 + lane*16; off < 32768; off += 4096)
                gl_lds16(bsrc + off, (char*)Bs4 + off);
        }
        __syncthreads();

        #pragma unroll
        for (int kkl = 0; kkl < 4; ++kkl) {
            int kkg = c*4 + kkl;
            half8 b[8];
            #pragma unroll
            for (int n = 0; n < 8; ++n) b[n] = bc8(Bs4[(kkl*8 + n)*64 + lane]);
            half8 p8 = bc8(Ps4[kkl*64 + lane]);
            #pragma unroll
            for (int t = 0; t < 4; ++t) {
                half8 q8 = bc8(Qs4[(wv*4 + t)*128 + kkg*4 + (lane >> 4)]);
                half8 x = p8 + q8;
                half8 z = 0;
                x = __builtin_elementwise_max(x, z);
                #pragma unroll
                for (int n = 0; n < 8; ++n)
                    acc[t][n] = __builtin_amdgcn_mfma_f32_16x16x32_f16(x, b[n], acc[t][n], 0, 0, 0);
            }
        }
    }

    _Float16* epi = (_Float16*)(smem + 36864);         // 16 s x 16 d x 64 j = 32 KB
    int cn = lane & 15, rhi = (lane >> 4) * 4;
    for (int half = 0; half < 2; ++half) {
        __syncthreads();
        #pragma unroll
        for (int t = 0; t < 4; ++t) {
            int dl = wv*4 + t;
            #pragma unroll
            for (int n = 0; n < 4; ++n) {
                int j = n*16 + cn;
                float4v v = acc[t][half*4 + n];
                #pragma unroll
                for (int r = 0; r < 4; ++r)
                    epi[((rhi + r)*16 + dl)*64 + j] = (_Float16)v[r];
            }
        }
        __syncthreads();
        int srow = tid >> 4, dl = tid & 15;
        const uint4* src = (const uint4*)(epi + tid*64);
        uint4* dst = (uint4*)(TT + ((size_t)((g*16 + srow)*384 + d0 + dl))*64 + half*32);
        #pragma unroll
        for (int q = 0; q < 8; ++q) dst[q] = src[q];
    }
}

// ---------------- attention ----------------
__global__ void k_att(const uint32_t* __restrict__ TT, const float* __restrict__ R,
                      const float* __restrict__ w2, const float* __restrict__ b2,
                      int off, float* __restrict__ ATT) {
    int p = blockIdx.x * 256 + threadIdx.x;            // < 147456
    int s = p / 384, d = p - s * 384;
    __shared__ float w2s[64];
    if (threadIdx.x < 64) w2s[threadIdx.x] = w2[threadIdx.x];
    __syncthreads();
    const uint4* tp = (const uint4*)(TT + (size_t)p*64 + off);
    const float* rp = R + s*64;
    float logit = b2[0];
    #pragma unroll
    for (int m = 0; m < 8; ++m) {
        uint4 tv = tp[m];
        uint32_t us[4] = {tv.x, tv.y, tv.z, tv.w};
        #pragma unroll
        for (int q = 0; q < 4; ++q) {
            U32H2 c; c.u = us[q];
            int j = m*8 + q*2;
            float h0 = fmaxf((float)c.f[0] + rp[j],   0.f);
            float h1 = fmaxf((float)c.f[1] + rp[j+1], 0.f);
            logit += h0*w2s[j] + h1*w2s[j+1];
        }
    }
    float a = 1.f / (1.f + __expf(-logit));
    ATT[p] = (s == d) ? 0.f : a;
}

// ---------------- agg[d][c] = sum_s ATT[s,d] * X[s][c]  (tiled, coalesced) ----------------
__global__ void __launch_bounds__(256)
k_agg(const float* __restrict__ ATT, const float* __restrict__ X,
      float* __restrict__ AGG) {
    int tid = threadIdx.x;
    int d0 = blockIdx.x * 16;
    __shared__ float att_s[16][17];
    float acc[16];
    #pragma unroll
    for (int dl = 0; dl < 16; ++dl) acc[dl] = 0.f;

    for (int s0 = 0; s0 < 384; s0 += 16) {
        __syncthreads();
        {
            int row = tid >> 4, col = tid & 15;
            att_s[row][col] = ATT[(s0 + row)*384 + d0 + col];
        }
        __syncthreads();
        #pragma unroll 4
        for (int ss = 0; ss < 16; ++ss) {
            float x = X[(s0 + ss)*256 + tid];
            #pragma unroll
            for (int dl = 0; dl < 16; ++dl) acc[dl] += att_s[ss][dl] * x;
        }
    }
    #pragma unroll
    for (int dl = 0; dl < 16; ++dl)
        AGG[(d0 + dl)*256 + tid] = acc[dl];
}

__global__ void k_x0r1(const float* __restrict__ AGG, const float* __restrict__ W,
                       const float* __restrict__ b, const float* __restrict__ a1W1,
                       const float* __restrict__ a1b1, const float* __restrict__ cc,
                       float* __restrict__ X0, float* __restrict__ R1) {
    int d = blockIdx.x, tid = threadIdx.x;
    __shared__ float ag[256];
    __shared__ float xs[256];
    ag[tid] = AGG[d*256 + tid];
    __syncthreads();
    float acc = b[tid];
    for (int i = 0; i < 256; ++i) acc += ag[i] * W[i*256 + tid];
    acc = fmaxf(acc, 0.f);
    X0[d*256 + tid] = acc;
    xs[tid] = acc;
    __syncthreads();
    if (tid < 64) {
        float r = a1b1[tid] + cc[64 + tid];
        for (int i = 0; i < 256; ++i) r += xs[i] * a1W1[(128+i)*64 + tid];
        R1[d*64 + tid] = r;
    }
}

__global__ void k_colsum(const float* __restrict__ ATT, float* __restrict__ CS) {
    int s = blockIdx.x, t = threadIdx.x;               // block 64
    float acc = 0.f;
    for (int d = t; d < 384; d += 64) acc += ATT[s*384 + d];
    for (int o = 32; o > 0; o >>= 1) acc += __shfl_down(acc, o, 64);
    if (t == 0) CS[s] = acc;
}

__global__ void k_v(const float* __restrict__ CS, const float* __restrict__ X0,
                    float* __restrict__ V) {
    int tid = threadIdx.x;
    __shared__ float cs[384];
    for (int q = tid; q < 384; q += 256) cs[q] = CS[q];
    __syncthreads();
    float acc = 0.f;
    for (int s = 0; s < 384; s += 4) {
        acc += cs[s]*X0[s*256 + tid] + cs[s+1]*X0[(s+1)*256 + tid]
             + cs[s+2]*X0[(s+2)*256 + tid] + cs[s+3]*X0[(s+3)*256 + tid];
    }
    V[tid] = acc;
}

__global__ void k_out(const float* __restrict__ V, const float* __restrict__ W,
                      const float* __restrict__ b, float* __restrict__ out) {
    int tid = threadIdx.x;
    __shared__ float vs[256];
    vs[tid] = V[tid];
    __syncthreads();
    float acc = 384.f * b[tid];
    for (int i = 0; i < 256; ++i) acc += vs[i] * W[i*256 + tid];
    out[tid] = acc;
}

extern "C" void kernel_launch(void* const* d_in, const int* in_sizes, int n_in,
                              void* d_out, int out_size, void* d_ws, size_t ws_size,
                              hipStream_t stream) {
    if (ws_size < WS_TOTAL * sizeof(uint32_t)) return;

    const float* z    = (const float*)d_in[0];
    const float* Wih  = (const float*)d_in[1];
    const float* Whh  = (const float*)d_in[2];
    const float* bih  = (const float*)d_in[3];
    const float* bhh  = (const float*)d_in[4];
    const float* egW1 = (const float*)d_in[5];
    const float* egb1 = (const float*)d_in[6];
    const float* egW2 = (const float*)d_in[7];
    const float* egb2 = (const float*)d_in[8];
    const float* a0W1 = (const float*)d_in[9];
    const float* a0b1 = (const float*)d_in[10];
    const float* a0W2 = (const float*)d_in[11];
    const float* a0b2 = (const float*)d_in[12];
    const float* a1W1 = (const float*)d_in[13];
    const float* a1b1 = (const float*)d_in[14];
    const float* a1W2 = (const float*)d_in[15];
    const float* a1b2 = (const float*)d_in[16];
    const float* c0W  = (const float*)d_in[17];
    const float* c0b  = (const float*)d_in[18];
    const float* c1W  = (const float*)d_in[19];
    const float* c1b  = (const float*)d_in[20];

    uint32_t* ws   = (uint32_t*)d_ws;
    uint32_t* WL   = ws + OFF_W16T;
    float*    gi   = (float*)(ws + OFF_GI);
    float*    cc   = (float*)(ws + OFF_CC);
    uint32_t* BF   = ws + OFF_BF;
    float*    nodes= (float*)(ws + OFF_NODES);
    uint32_t* PF   = ws + OFF_PF;
    uint32_t* QF   = ws + OFF_QF;
    float*    R0   = (float*)(ws + OFF_R0);
    float*    R1   = (float*)(ws + OFF_R1);
    uint32_t* TT   = ws + OFF_TT;
    float*    ATT0 = (float*)(ws + OFF_ATT0);
    float*    ATT1 = (float*)(ws + OFF_ATT1);
    float*    AGG  = (float*)(ws + OFF_AGG);
    float*    X0   = (float*)(ws + OFF_X0);
    float*    CS   = (float*)(ws + OFF_CS);
    float*    V    = (float*)(ws + OFF_V);
    float*    out  = (float*)d_out;

    hipLaunchKernelGGL(k_prep_w16,    dim3(96),  dim3(256), 0, stream, Whh, WL);
    hipLaunchKernelGGL(k_prep_gi,     dim3(3),   dim3(256), 0, stream, z, Wih, bih, gi);
    hipLaunchKernelGGL(k_prep_cc,     dim3(1),   dim3(128), 0, stream, egb2, a0W1, a1W1, cc);
    hipLaunchKernelGGL(k_prep_w2a,    dim3(256), dim3(256), 0, stream, egW2, a0W1, a1W1, BF);
    hipLaunchKernelGGL(k_gru,         dim3(1),   dim3(512), 0, stream, gi, bhh, WL, nodes);
    hipLaunchKernelGGL(k_pq,          dim3(96),  dim3(256), 0, stream, nodes, egW1, egb1, a0W1, a0b1, cc, PF, QF, R0);
    hipLaunchKernelGGL(k_phaseA_mfma, dim3(24, 24), dim3(256), 0, stream, PF, QF, BF, TT);
    hipLaunchKernelGGL(k_att,         dim3(576), dim3(256), 0, stream, TT, R0, a0W2, a0b2, 0,  ATT0);
    hipLaunchKernelGGL(k_agg,         dim3(24),  dim3(256), 0, stream, ATT0, nodes, AGG);
    hipLaunchKernelGGL(k_x0r1,        dim3(384), dim3(256), 0, stream, AGG, c0W, c0b, a1W1, a1b1, cc, X0, R1);
    hipLaunchKernelGGL(k_att,         dim3(576), dim3(256), 0, stream, TT, R1, a1W2, a1b2, 32, ATT1);
    hipLaunchKernelGGL(k_colsum,      dim3(384), dim3(64),  0, stream, ATT1, CS);
    hipLaunchKernelGGL(k_v,           dim3(1),   dim3(256), 0, stream, CS, X0, V);
    hipLaunchKernelGGL(k_out,         dim3(1),   dim3(256), 0, stream, V, c1W, c1b, out);
}

// Round 7
// 795.816 us; speedup vs baseline: 1.2350x; 1.2350x over previous
//
#include <hip/hip_runtime.h>
#include <hip/hip_fp16.h>
#include <cstdint>

#define DEV static __device__ __forceinline__

typedef _Float16 h2v __attribute__((ext_vector_type(2)));
typedef _Float16 half8 __attribute__((ext_vector_type(8)));
typedef float float4v __attribute__((ext_vector_type(4)));

union U32H2 { uint32_t u; _Float16 f[2]; };

DEV uint32_t pack_f2(float a, float b) {
    auto p = __builtin_amdgcn_cvt_pkrtz(a, b);
    return __builtin_bit_cast(uint32_t, p);
}

DEV half8 bc8(uint4 v) { return __builtin_bit_cast(half8, v); }

DEV float sigmoidf_(float x) { return 1.0f / (1.0f + __expf(-x)); }
DEV float tanh_fast(float x) { float e = __expf(-2.0f*x); return (1.0f - e) / (1.0f + e); }

DEV void gl_lds16(const void* gsrc, void* ldst) {
    __builtin_amdgcn_global_load_lds(
        (const __attribute__((address_space(1))) uint32_t*)gsrc,
        (__attribute__((address_space(3))) uint32_t*)ldst, 16, 0, 0);
}

// ---------------- workspace layout (uint32 units) ----------------
// N=384 H=256 Z=128 ED=128 AH=64
static const size_t OFF_W16T  = 0;          // 98304  : Whh f16 as MFMA A-fragments (k_gru layout)
static const size_t OFF_GI    = 98304;      // 768
static const size_t OFF_CC    = 99072;      // 128
static const size_t OFF_BF    = 99200;      // 65536  : W2A in MFMA B-frag layout
static const size_t OFF_NODES = 164736;     // 98304  : GRU outputs fp32 [384][256]
static const size_t OFF_PF    = 263040;     // 196608 : P in MFMA A-frag layout
static const size_t OFF_QF    = 459648;     // 196608 : Q natural f16 [384][512 u32]
static const size_t OFF_R0    = 656256;     // 24576
static const size_t OFF_R1    = 680832;     // 24576
static const size_t OFF_TT    = 705408;     // 9437184: T f16 [s][d][64 u32]
static const size_t OFF_ATT0  = 10142592;   // 147456
static const size_t OFF_ATT1  = 10290048;   // 147456
static const size_t OFF_AGG   = 10437504;   // 98304
static const size_t OFF_X0    = 10535808;   // 98304
static const size_t OFF_CS    = 10634112;   // 384
static const size_t OFF_V     = 10634496;   // 256
static const size_t WS_TOTAL  = 10634752;   // u32 elems (~42.5 MB)

// ---------------- prep kernels ----------------
// WL: Whh as MFMA 16x16x32 A-fragments. uint4 index o4 = c*512 + t (c=0..47, t=0..511)
// chunk c: row-tile rt = c>>3 (0..5), k-tile kt = c&7. thread t (wave wv=t>>6, lane):
// holds A[m][k] with m = (wv*6+rt)*16 + (lane&15), k = kt*32 + (lane>>4)*8 .. +7 as 8 f16.
__global__ void k_prep_w16(const float* __restrict__ Whh, uint32_t* __restrict__ WL) {
    int o4 = blockIdx.x * 256 + threadIdx.x;           // < 24576
    int c = o4 >> 9, t = o4 & 511;
    int rt = c >> 3, kt = c & 7;
    int lane = t & 63, wv = t >> 6;
    int m = (wv*6 + rt)*16 + (lane & 15);
    int k0 = kt*32 + (lane >> 4)*8;
    const float* src = Whh + m*256 + k0;
    uint4 o;
    o.x = pack_f2(src[0], src[1]);
    o.y = pack_f2(src[2], src[3]);
    o.z = pack_f2(src[4], src[5]);
    o.w = pack_f2(src[6], src[7]);
    ((uint4*)WL)[o4] = o;
}

__global__ void k_prep_gi(const float* __restrict__ z, const float* __restrict__ Wih,
                          const float* __restrict__ bih, float* __restrict__ gi) {
    int o = blockIdx.x * 256 + threadIdx.x;            // < 768
    float acc = bih[o];
    for (int i = 0; i < 128; ++i) acc += Wih[o*128 + i] * z[i];
    gi[o] = acc;
}

__global__ void k_prep_cc(const float* __restrict__ eg_b2, const float* __restrict__ a0W1,
                          const float* __restrict__ a1W1, float* __restrict__ cc) {
    int t = threadIdx.x;                               // < 128
    const float* A = (t < 64) ? a0W1 : a1W1;
    int j = t & 63;
    float acc = 0.f;
    for (int i = 0; i < 128; ++i) acc += eg_b2[i] * A[i*64 + j];
    cc[t] = acc;
}

// W2A[k][n] in MFMA B-frag layout
__global__ void k_prep_w2a(const float* __restrict__ eg_W2, const float* __restrict__ a0W1,
                           const float* __restrict__ a1W1, uint32_t* __restrict__ BF) {
    int idx = blockIdx.x * 256 + threadIdx.x;          // < 65536
    int k2 = idx >> 7, n = idx & 127;
    const float* A = (n < 64) ? (a0W1 + n) : (a1W1 + (n - 64));
    const float* w0 = eg_W2 + (2*k2) * 128;
    float a = 0.f, b = 0.f;
    for (int i = 0; i < 128; ++i) {
        float av = A[i*64];
        a += w0[i] * av;
        b += w0[128 + i] * av;
    }
    int kk = k2 >> 4, jgrp = (k2 >> 2) & 3, sub = k2 & 3;
    int lane = jgrp*16 + (n & 15), t = n >> 4;
    BF[((kk*8 + t)*64 + lane)*4 + sub] = pack_f2(a, b);
}

// ---------------- GRU: 512 threads; Whh in AGPRs as MFMA A-operands ----------------
// wave wv: row-tiles wv*6..wv*6+5. gh = Whh @ h via 48 mfma_16x16x32_f16 per wave.
// B = h broadcast into all 16 cols; lanes with col==0 extract D (4 rows each).
__global__ void __launch_bounds__(512, 2)
k_gru(const float* __restrict__ gi, const float* __restrict__ bhh,
      const uint32_t* __restrict__ WL, float* __restrict__ nodes) {
    int tid = threadIdx.x;
    int lane = tid & 63, wv = tid >> 6;
    __shared__ __align__(16) _Float16 hh16[256];
    __shared__ float ghs[768];

    // load 48 A-frags, pin each 32-bit component to the AGPR class
    // (scalar tied "+a" — 128-bit tuples are unsupported "indirect" ties)
    uint4 w[48];
    const uint4* wl4 = (const uint4*)WL;
    #pragma unroll
    for (int c = 0; c < 48; ++c) w[c] = wl4[c*512 + tid];
    #pragma unroll
    for (int c = 0; c < 48; ++c)
        asm volatile("" : "+a"(w[c].x), "+a"(w[c].y), "+a"(w[c].z), "+a"(w[c].w));

    float gir = 0.f, giz = 0.f, gin = 0.f, bh0 = 0.f, bh1 = 0.f, bh2 = 0.f;
    if (tid < 256) {
        gir = gi[tid]; giz = gi[256 + tid]; gin = gi[512 + tid];
        bh0 = bhh[tid]; bh1 = bhh[256 + tid]; bh2 = bhh[512 + tid];
    }
    float h = 0.f;
    if (tid < 128) ((uint32_t*)hh16)[tid] = 0u;
    __syncthreads();

    int kq = lane >> 4;                                // 0..3
    bool writer = (lane & 15) == 0;
    int rowbase = wv*6*16 + kq*4;

    for (int t = 0; t < 384; ++t) {
        float4v d[6];
        #pragma unroll
        for (int rt = 0; rt < 6; ++rt) d[rt] = 0.f;

        half8 bcur = bc8(*(const uint4*)(hh16 + 0*32 + kq*8));
        #pragma unroll
        for (int kt = 0; kt < 8; ++kt) {
            half8 bnext;
            if (kt < 7) bnext = bc8(*(const uint4*)(hh16 + (kt+1)*32 + kq*8));
            #pragma unroll
            for (int rt = 0; rt < 6; ++rt)
                d[rt] = __builtin_amdgcn_mfma_f32_16x16x32_f16(
                    bc8(w[rt*8 + kt]), bcur, d[rt], 0, 0, 0);
            bcur = bnext;
        }

        if (writer) {
            #pragma unroll
            for (int rt = 0; rt < 6; ++rt)
                *(float4v*)(ghs + rowbase + rt*16) = d[rt];
        }
        __syncthreads();
        if (tid < 256) {
            float a0 = ghs[tid]       + bh0;
            float a1 = ghs[256 + tid] + bh1;
            float a2 = ghs[512 + tid] + bh2;
            float rg = sigmoidf_(gir + a0);
            float u  = sigmoidf_(giz + a1);
            float n  = tanh_fast(gin + rg * a2);
            h = (1.f - u) * n + u * h;
            hh16[tid] = (_Float16)h;
            nodes[t*256 + tid] = h;
        }
        __syncthreads();
    }
}

// ---------------- P (A-frag layout), Q (natural f16), R0 ----------------
__global__ void k_pq(const float* __restrict__ nodes, const float* __restrict__ eg_W1,
                     const float* __restrict__ eg_b1, const float* __restrict__ a0W1,
                     const float* __restrict__ a0b1, const float* __restrict__ cc,
                     uint32_t* __restrict__ PF, uint32_t* __restrict__ QF,
                     float* __restrict__ R0) {
    int tid = threadIdx.x;
    int s0 = blockIdx.x * 4;
    __shared__ float ns[4][256];
    #pragma unroll
    for (int q = 0; q < 4; ++q) ns[q][tid] = nodes[(s0+q)*256 + tid];
    __syncthreads();

    int k0 = tid * 4;
    float acc[4][4];
    #pragma unroll
    for (int q = 0; q < 4; ++q) { acc[q][0]=0;acc[q][1]=0;acc[q][2]=0;acc[q][3]=0; }
    for (int i = 0; i < 256; ++i) {
        float4 wv = *(const float4*)&eg_W1[i*1024 + k0];
        #pragma unroll
        for (int q = 0; q < 4; ++q) {
            float nv = ns[q][i];
            acc[q][0] += nv*wv.x; acc[q][1] += nv*wv.y;
            acc[q][2] += nv*wv.z; acc[q][3] += nv*wv.w;
        }
    }
    float4 bv = *(const float4*)&eg_b1[k0];
    {
        int kk = k0 >> 5;
        int lgrp = ((k0 >> 3) & 3) * 16;
        int sub = (k0 & 7) >> 1;                       // 0 or 2
        #pragma unroll
        for (int q = 0; q < 4; ++q) {
            int s = s0 + q, g = s >> 4, srow = s & 15;
            uint2 pw;
            pw.x = pack_f2(acc[q][0] + bv.x, acc[q][1] + bv.y);
            pw.y = pack_f2(acc[q][2] + bv.z, acc[q][3] + bv.w);
            *(uint2*)(PF + (((g*32 + kk)*64 + lgrp + srow) << 2) + sub) = pw;
        }
    }

    #pragma unroll
    for (int q = 0; q < 4; ++q) { acc[q][0]=0;acc[q][1]=0;acc[q][2]=0;acc[q][3]=0; }
    for (int i = 0; i < 256; ++i) {
        float4 wv = *(const float4*)&eg_W1[(256+i)*1024 + k0];
        #pragma unroll
        for (int q = 0; q < 4; ++q) {
            float nv = ns[q][i];
            acc[q][0] += nv*wv.x; acc[q][1] += nv*wv.y;
            acc[q][2] += nv*wv.z; acc[q][3] += nv*wv.w;
        }
    }
    #pragma unroll
    for (int q = 0; q < 4; ++q) {
        uint2 pw;
        pw.x = pack_f2(acc[q][0], acc[q][1]);
        pw.y = pack_f2(acc[q][2], acc[q][3]);
        ((uint2*)QF)[(s0+q)*256 + tid] = pw;           // QF[d][k/2], natural order
    }

    int srow = tid >> 6, j = tid & 63;
    float racc = a0b1[j] + cc[j];
    for (int i = 0; i < 256; ++i) racc += ns[srow][i] * a0W1[(128+i)*64 + j];
    R0[(s0+srow)*64 + j] = racc;
}

// ---------------- phase A (MFMA): T[s,d,:] = relu(P[s]+Q[d]) @ W2A ----------------
__global__ void __launch_bounds__(256, 2)
k_phaseA_mfma(const uint32_t* __restrict__ PF, const uint32_t* __restrict__ QF,
              const uint32_t* __restrict__ BF, uint32_t* __restrict__ TT) {
    __shared__ __align__(16) char smem[69632];
    uint4* Qs4 = (uint4*)smem;                         // 16 d x 128 uint4 = 32 KB
    uint4* Ps4 = (uint4*)(smem + 32768);               // 4 kk x 64 lane = 4 KB
    uint4* Bs4 = (uint4*)(smem + 36864);               // 4 kk x 8 t x 64 lane = 32 KB

    int tid = threadIdx.x;
    int lane = tid & 63, wv = tid >> 6;
    int g = blockIdx.x, d0 = blockIdx.y * 16;

    {
        const char* src = (const char*)(QF + (size_t)d0 * 512);
        for (int off = wv*1024 + lane*16; off < 32768; off += 4096)
            gl_lds16(src + off, (char*)Qs4 + off);
    }

    float4v acc[4][8];
    #pragma unroll
    for (int t = 0; t < 4; ++t)
        #pragma unroll
        for (int n = 0; n < 8; ++n) acc[t][n] = 0.f;

    for (int c = 0; c < 8; ++c) {
        __syncthreads();
        {
            const char* psrc = (const char*)(PF + (size_t)(g*32 + c*4) * 256);
            for (int off = wv*1024 + lane*16; off < 4096; off += 4096)
                gl_lds16(psrc + off, (char*)Ps4 + off);
            const char* bsrc = (const char*)(BF + (size_t)c * 8192);
            for (int off = wv*1024 + lane*16; off < 32768; off += 4096)
                gl_lds16(bsrc + off, (char*)Bs4 + off);
        }
        __syncthreads();

        #pragma unroll
        for (int kkl = 0; kkl < 4; ++kkl) {
            int kkg = c*4 + kkl;
            half8 b[8];
            #pragma unroll
            for (int n = 0; n < 8; ++n) b[n] = bc8(Bs4[(kkl*8 + n)*64 + lane]);
            half8 p8 = bc8(Ps4[kkl*64 + lane]);
            #pragma unroll
            for (int t = 0; t < 4; ++t) {
                half8 q8 = bc8(Qs4[(wv*4 + t)*128 + kkg*4 + (lane >> 4)]);
                half8 x = p8 + q8;
                half8 z = 0;
                x = __builtin_elementwise_max(x, z);
                #pragma unroll
                for (int n = 0; n < 8; ++n)
                    acc[t][n] = __builtin_amdgcn_mfma_f32_16x16x32_f16(x, b[n], acc[t][n], 0, 0, 0);
            }
        }
    }

    _Float16* epi = (_Float16*)(smem + 36864);         // 16 s x 16 d x 64 j = 32 KB
    int cn = lane & 15, rhi = (lane >> 4) * 4;
    for (int half = 0; half < 2; ++half) {
        __syncthreads();
        #pragma unroll
        for (int t = 0; t < 4; ++t) {
            int dl = wv*4 + t;
            #pragma unroll
            for (int n = 0; n < 4; ++n) {
                int j = n*16 + cn;
                float4v v = acc[t][half*4 + n];
                #pragma unroll
                for (int r = 0; r < 4; ++r)
                    epi[((rhi + r)*16 + dl)*64 + j] = (_Float16)v[r];
            }
        }
        __syncthreads();
        int srow = tid >> 4, dl = tid & 15;
        const uint4* src = (const uint4*)(epi + tid*64);
        uint4* dst = (uint4*)(TT + ((size_t)((g*16 + srow)*384 + d0 + dl))*64 + half*32);
        #pragma unroll
        for (int q = 0; q < 8; ++q) dst[q] = src[q];
    }
}

// ---------------- attention ----------------
__global__ void k_att(const uint32_t* __restrict__ TT, const float* __restrict__ R,
                      const float* __restrict__ w2, const float* __restrict__ b2,
                      int off, float* __restrict__ ATT) {
    int p = blockIdx.x * 256 + threadIdx.x;            // < 147456
    int s = p / 384, d = p - s * 384;
    __shared__ float w2s[64];
    if (threadIdx.x < 64) w2s[threadIdx.x] = w2[threadIdx.x];
    __syncthreads();
    const uint4* tp = (const uint4*)(TT + (size_t)p*64 + off);
    const float* rp = R + s*64;
    float logit = b2[0];
    #pragma unroll
    for (int m = 0; m < 8; ++m) {
        uint4 tv = tp[m];
        uint32_t us[4] = {tv.x, tv.y, tv.z, tv.w};
        #pragma unroll
        for (int q = 0; q < 4; ++q) {
            U32H2 c; c.u = us[q];
            int j = m*8 + q*2;
            float h0 = fmaxf((float)c.f[0] + rp[j],   0.f);
            float h1 = fmaxf((float)c.f[1] + rp[j+1], 0.f);
            logit += h0*w2s[j] + h1*w2s[j+1];
        }
    }
    float a = 1.f / (1.f + __expf(-logit));
    ATT[p] = (s == d) ? 0.f : a;
}

// ---------------- agg[d][c] = sum_s ATT[s,d] * X[s][c]  (tiled, coalesced) ----------------
__global__ void __launch_bounds__(256)
k_agg(const float* __restrict__ ATT, const float* __restrict__ X,
      float* __restrict__ AGG) {
    int tid = threadIdx.x;
    int d0 = blockIdx.x * 16;
    __shared__ float att_s[16][17];
    float acc[16];
    #pragma unroll
    for (int dl = 0; dl < 16; ++dl) acc[dl] = 0.f;

    for (int s0 = 0; s0 < 384; s0 += 16) {
        __syncthreads();
        {
            int row = tid >> 4, col = tid & 15;
            att_s[row][col] = ATT[(s0 + row)*384 + d0 + col];
        }
        __syncthreads();
        #pragma unroll 4
        for (int ss = 0; ss < 16; ++ss) {
            float x = X[(s0 + ss)*256 + tid];
            #pragma unroll
            for (int dl = 0; dl < 16; ++dl) acc[dl] += att_s[ss][dl] * x;
        }
    }
    #pragma unroll
    for (int dl = 0; dl < 16; ++dl)
        AGG[(d0 + dl)*256 + tid] = acc[dl];
}

__global__ void k_x0r1(const float* __restrict__ AGG, const float* __restrict__ W,
                       const float* __restrict__ b, const float* __restrict__ a1W1,
                       const float* __restrict__ a1b1, const float* __restrict__ cc,
                       float* __restrict__ X0, float* __restrict__ R1) {
    int d = blockIdx.x, tid = threadIdx.x;
    __shared__ float ag[256];
    __shared__ float xs[256];
    ag[tid] = AGG[d*256 + tid];
    __syncthreads();
    float acc = b[tid];
    for (int i = 0; i < 256; ++i) acc += ag[i] * W[i*256 + tid];
    acc = fmaxf(acc, 0.f);
    X0[d*256 + tid] = acc;
    xs[tid] = acc;
    __syncthreads();
    if (tid < 64) {
        float r = a1b1[tid] + cc[64 + tid];
        for (int i = 0; i < 256; ++i) r += xs[i] * a1W1[(128+i)*64 + tid];
        R1[d*64 + tid] = r;
    }
}

__global__ void k_colsum(const float* __restrict__ ATT, float* __restrict__ CS) {
    int s = blockIdx.x, t = threadIdx.x;               // block 64
    float acc = 0.f;
    for (int d = t; d < 384; d += 64) acc += ATT[s*384 + d];
    for (int o = 32; o > 0; o >>= 1) acc += __shfl_down(acc, o, 64);
    if (t == 0) CS[s] = acc;
}

__global__ void k_v(const float* __restrict__ CS, const float* __restrict__ X0,
                    float* __restrict__ V) {
    int tid = threadIdx.x;
    __shared__ float cs[384];
    for (int q = tid; q < 384; q += 256) cs[q] = CS[q];
    __syncthreads();
    float acc = 0.f;
    for (int s = 0; s < 384; s += 4) {
        acc += cs[s]*X0[s*256 + tid] + cs[s+1]*X0[(s+1)*256 + tid]
             + cs[s+2]*X0[(s+2)*256 + tid] + cs[s+3]*X0[(s+3)*256 + tid];
    }
    V[tid] = acc;
}

__global__ void k_out(const float* __restrict__ V, const float* __restrict__ W,
                      const float* __restrict__ b, float* __restrict__ out) {
    int tid = threadIdx.x;
    __shared__ float vs[256];
    vs[tid] = V[tid];
    __syncthreads();
    float acc = 384.f * b[tid];
    for (int i = 0; i < 256; ++i) acc += vs[i] * W[i*256 + tid];
    out[tid] = acc;
}

extern "C" void kernel_launch(void* const* d_in, const int* in_sizes, int n_in,
                              void* d_out, int out_size, void* d_ws, size_t ws_size,
                              hipStream_t stream) {
    if (ws_size < WS_TOTAL * sizeof(uint32_t)) return;

    const float* z    = (const float*)d_in[0];
    const float* Wih  = (const float*)d_in[1];
    const float* Whh  = (const float*)d_in[2];
    const float* bih  = (const float*)d_in[3];
    const float* bhh  = (const float*)d_in[4];
    const float* egW1 = (const float*)d_in[5];
    const float* egb1 = (const float*)d_in[6];
    const float* egW2 = (const float*)d_in[7];
    const float* egb2 = (const float*)d_in[8];
    const float* a0W1 = (const float*)d_in[9];
    const float* a0b1 = (const float*)d_in[10];
    const float* a0W2 = (const float*)d_in[11];
    const float* a0b2 = (const float*)d_in[12];
    const float* a1W1 = (const float*)d_in[13];
    const float* a1b1 = (const float*)d_in[14];
    const float* a1W2 = (const float*)d_in[15];
    const float* a1b2 = (const float*)d_in[16];
    const float* c0W  = (const float*)d_in[17];
    const float* c0b  = (const float*)d_in[18];
    const float* c1W  = (const float*)d_in[19];
    const float* c1b  = (const float*)d_in[20];

    uint32_t* ws   = (uint32_t*)d_ws;
    uint32_t* WL   = ws + OFF_W16T;
    float*    gi   = (float*)(ws + OFF_GI);
    float*    cc   = (float*)(ws + OFF_CC);
    uint32_t* BF   = ws + OFF_BF;
    float*    nodes= (float*)(ws + OFF_NODES);
    uint32_t* PF   = ws + OFF_PF;
    uint32_t* QF   = ws + OFF_QF;
    float*    R0   = (float*)(ws + OFF_R0);
    float*    R1   = (float*)(ws + OFF_R1);
    uint32_t* TT   = ws + OFF_TT;
    float*    ATT0 = (float*)(ws + OFF_ATT0);
    float*    ATT1 = (float*)(ws + OFF_ATT1);
    float*    AGG  = (float*)(ws + OFF_AGG);
    float*    X0   = (float*)(ws + OFF_X0);
    float*    CS   = (float*)(ws + OFF_CS);
    float*    V    = (float*)(ws + OFF_V);
    float*    out  = (float*)d_out;

    hipLaunchKernelGGL(k_prep_w16,    dim3(96),  dim3(256), 0, stream, Whh, WL);
    hipLaunchKernelGGL(k_prep_gi,     dim3(3),   dim3(256), 0, stream, z, Wih, bih, gi);
    hipLaunchKernelGGL(k_prep_cc,     dim3(1),   dim3(128), 0, stream, egb2, a0W1, a1W1, cc);
    hipLaunchKernelGGL(k_prep_w2a,    dim3(256), dim3(256), 0, stream, egW2, a0W1, a1W1, BF);
    hipLaunchKernelGGL(k_gru,         dim3(1),   dim3(512), 0, stream, gi, bhh, WL, nodes);
    hipLaunchKernelGGL(k_pq,          dim3(96),  dim3(256), 0, stream, nodes, egW1, egb1, a0W1, a0b1, cc, PF, QF, R0);
    hipLaunchKernelGGL(k_phaseA_mfma, dim3(24, 24), dim3(256), 0, stream, PF, QF, BF, TT);
    hipLaunchKernelGGL(k_att,         dim3(576), dim3(256), 0, stream, TT, R0, a0W2, a0b2, 0,  ATT0);
    hipLaunchKernelGGL(k_agg,         dim3(24),  dim3(256), 0, stream, ATT0, nodes, AGG);
    hipLaunchKernelGGL(k_x0r1,        dim3(384), dim3(256), 0, stream, AGG, c0W, c0b, a1W1, a1b1, cc, X0, R1);
    hipLaunchKernelGGL(k_att,         dim3(576), dim3(256), 0, stream, TT, R1, a1W2, a1b2, 32, ATT1);
    hipLaunchKernelGGL(k_colsum,      dim3(384), dim3(64),  0, stream, ATT1, CS);
    hipLaunchKernelGGL(k_v,           dim3(1),   dim3(256), 0, stream, CS, X0, V);
    hipLaunchKernelGGL(k_out,         dim3(1),   dim3(256), 0, stream, V, c1W, c1b, out);
}